// Round 8
// baseline (38.599 us; speedup 1.0000x reference)
//
#include <hip/hip_runtime.h>
#include <hip/hip_bf16.h>

#define BS 512
#define MARGIN 0.5f

using short8 = __attribute__((ext_vector_type(8))) short;
using f32x4 = __attribute__((ext_vector_type(4))) float;

__device__ inline short bf16_rne(float x) {
    __hip_bfloat16 h = __float2bfloat16(x);
    return *(short*)&h;
}

// Kernel B (fused normalize+dist): dist[i][j] = sqrt(max(2 - 2*dot_raw*inv_i*inv_j, 0)).
// One wave per 32x32 tile. Raw fp32 rows loaded fragment-shaped, converted to bf16
// in-register, MFMA'd; row norms computed in-wave (shfl chunk-reduce); rescale in
// epilogue. Block (0,0) zeroes done_g for ktriplet.
__global__ __launch_bounds__(64) void kdistf(const float* __restrict__ pred,
                                             float* __restrict__ dist,
                                             unsigned int* __restrict__ done_g) {
    const int lane = threadIdx.x;
    if (blockIdx.x == 0 && blockIdx.y == 0 && lane == 0) *done_g = 0u;
    const int r0 = blockIdx.y * 32;
    const int c0 = blockIdx.x * 32;
    const int rl = lane & 15;
    const int koff = (lane >> 4) * 8;

    const float* A0 = pred + (r0 + rl) * BS;
    const float* A1 = pred + (r0 + 16 + rl) * BS;
    const float* B0 = pred + (c0 + rl) * BS;
    const float* B1 = pred + (c0 + 16 + rl) * BS;

    f32x4 acc00 = {0.f, 0.f, 0.f, 0.f};
    f32x4 acc01 = {0.f, 0.f, 0.f, 0.f};
    f32x4 acc10 = {0.f, 0.f, 0.f, 0.f};
    f32x4 acc11 = {0.f, 0.f, 0.f, 0.f};
    float na0 = 0.f, na1 = 0.f, nb0 = 0.f, nb1 = 0.f;

#pragma unroll 4
    for (int ks = 0; ks < 16; ++ks) {
        const int k = ks * 32 + koff;
        const f32x4 a0l = *(const f32x4*)(A0 + k);
        const f32x4 a0h = *(const f32x4*)(A0 + k + 4);
        const f32x4 a1l = *(const f32x4*)(A1 + k);
        const f32x4 a1h = *(const f32x4*)(A1 + k + 4);
        const f32x4 b0l = *(const f32x4*)(B0 + k);
        const f32x4 b0h = *(const f32x4*)(B0 + k + 4);
        const f32x4 b1l = *(const f32x4*)(B1 + k);
        const f32x4 b1h = *(const f32x4*)(B1 + k + 4);

        short8 sa0, sa1, sb0, sb1;
#pragma unroll
        for (int j = 0; j < 4; ++j) {
            na0 += a0l[j] * a0l[j] + a0h[j] * a0h[j];
            na1 += a1l[j] * a1l[j] + a1h[j] * a1h[j];
            nb0 += b0l[j] * b0l[j] + b0h[j] * b0h[j];
            nb1 += b1l[j] * b1l[j] + b1h[j] * b1h[j];
            sa0[j] = bf16_rne(a0l[j]); sa0[4 + j] = bf16_rne(a0h[j]);
            sa1[j] = bf16_rne(a1l[j]); sa1[4 + j] = bf16_rne(a1h[j]);
            sb0[j] = bf16_rne(b0l[j]); sb0[4 + j] = bf16_rne(b0h[j]);
            sb1[j] = bf16_rne(b1l[j]); sb1[4 + j] = bf16_rne(b1h[j]);
        }
        acc00 = __builtin_amdgcn_mfma_f32_16x16x32_bf16(sa0, sb0, acc00, 0, 0, 0);
        acc01 = __builtin_amdgcn_mfma_f32_16x16x32_bf16(sa0, sb1, acc01, 0, 0, 0);
        acc10 = __builtin_amdgcn_mfma_f32_16x16x32_bf16(sa1, sb0, acc10, 0, 0, 0);
        acc11 = __builtin_amdgcn_mfma_f32_16x16x32_bf16(sa1, sb1, acc11, 0, 0, 0);
    }

    // chunk-reduce norms: lanes {rl, rl+16, rl+32, rl+48} hold row r0+rl's 4 chunks
    na0 += __shfl_xor(na0, 16, 64); na0 += __shfl_xor(na0, 32, 64);
    na1 += __shfl_xor(na1, 16, 64); na1 += __shfl_xor(na1, 32, 64);
    nb0 += __shfl_xor(nb0, 16, 64); nb0 += __shfl_xor(nb0, 32, 64);
    nb1 += __shfl_xor(nb1, 16, 64); nb1 += __shfl_xor(nb1, 32, 64);
    const float ia0 = 1.0f / fmaxf(sqrtf(na0), 1e-10f);
    const float ia1 = 1.0f / fmaxf(sqrtf(na1), 1e-10f);
    const float ib0 = 1.0f / fmaxf(sqrtf(nb0), 1e-10f);
    const float ib1 = 1.0f / fmaxf(sqrtf(nb1), 1e-10f);

    // C/D layout: col = lane&15, row = (lane>>4)*4 + reg  [m89]
    const int rbase = (lane >> 4) * 4;
#pragma unroll
    for (int fr = 0; fr < 2; ++fr) {
        const float iaSel = (fr == 0) ? ia0 : ia1;
#pragma unroll
        for (int fc = 0; fc < 2; ++fc) {
            f32x4 v = (fr == 0) ? (fc == 0 ? acc00 : acc01) : (fc == 0 ? acc10 : acc11);
            const int col = c0 + fc * 16 + rl;
            const float icol = (fc == 0) ? ib0 : ib1;
#pragma unroll
            for (int r = 0; r < 4; ++r) {
                const float irow = __shfl(iaSel, rbase + r, 64);
                const int row = r0 + fr * 16 + rbase + r;
                float d2 = 2.0f - 2.0f * v[r] * irow * icol;
                d2 = fmaxf(d2, 0.f);
                dist[row * BS + col] = sqrtf(d2);
            }
        }
    }
}

// Kernel C: one block per anchor i. All-scalar registers (no arrays -> no scratch),
// partial unroll (I-cache friendly), readlane with uniform runtime index, ballot+
// popcount counting. Per-anchor partial stores + done-counter; last block reduces.
__global__ __launch_bounds__(256) void ktriplet(const float* __restrict__ dist,
                                                const int* __restrict__ target,
                                                float* __restrict__ psum,
                                                float* __restrict__ pcnt,
                                                unsigned int* __restrict__ done_g,
                                                float* __restrict__ out) {
    const int i = blockIdx.x;
    const int tid = threadIdx.x;
    const int lane = tid & 63;
    const int w = tid >> 6;
    __shared__ float sbuf[4];
    __shared__ float cbuf[4];
    __shared__ unsigned int slast;

    float sum = 0.f;
    float cnt = 0.f;

    if (target[i] == 1) {
        const float* drow = dist + i * BS;
        // k-role distances (negatives), named scalars, sentinel +1e30 when masked
        const float d0 = drow[lane];       const float dk0 = (target[lane] == 0)       ? d0 : 1e30f;
        const float d1 = drow[lane + 64];  const float dk1 = (target[lane + 64] == 0)  ? d1 : 1e30f;
        const float d2 = drow[lane + 128]; const float dk2 = (target[lane + 128] == 0) ? d2 : 1e30f;
        const float d3 = drow[lane + 192]; const float dk3 = (target[lane + 192] == 0) ? d3 : 1e30f;
        const float d4 = drow[lane + 256]; const float dk4 = (target[lane + 256] == 0) ? d4 : 1e30f;
        const float d5 = drow[lane + 320]; const float dk5 = (target[lane + 320] == 0) ? d5 : 1e30f;
        const float d6 = drow[lane + 384]; const float dk6 = (target[lane + 384] == 0) ? d6 : 1e30f;
        const float d7 = drow[lane + 448]; const float dk7 = (target[lane + 448] == 0) ? d7 : 1e30f;
        // j-role (positives), this wave's 128 js, margin folded, sentinel -1e9
        const int ja = w * 128 + lane;
        const int jb = ja + 64;
        const float jv0 = (target[ja] == 1 && ja != i) ? drow[ja] + MARGIN : -1e9f;
        const float jv1 = (target[jb] == 1 && jb != i) ? drow[jb] + MARGIN : -1e9f;

        float sA = 0.f, sB = 0.f, sC = 0.f, sD = 0.f;
        unsigned int cw = 0;  // wave-uniform SGPR accumulator (ballot popcounts)

#define HINGE(TJ, DK, SX)                                   \
    do {                                                    \
        const float v_ = (TJ) - (DK);                       \
        SX += fmaxf(v_, 0.f);                               \
        cw += (unsigned int)__popcll(__ballot(v_ > 0.f));   \
    } while (0)

#pragma unroll 4
        for (int jj = 0; jj < 64; ++jj) {
            const float tj0 = __int_as_float(
                __builtin_amdgcn_readlane(__float_as_int(jv0), jj));
            HINGE(tj0, dk0, sA); HINGE(tj0, dk1, sB);
            HINGE(tj0, dk2, sC); HINGE(tj0, dk3, sD);
            HINGE(tj0, dk4, sA); HINGE(tj0, dk5, sB);
            HINGE(tj0, dk6, sC); HINGE(tj0, dk7, sD);
            const float tj1 = __int_as_float(
                __builtin_amdgcn_readlane(__float_as_int(jv1), jj));
            HINGE(tj1, dk0, sA); HINGE(tj1, dk1, sB);
            HINGE(tj1, dk2, sC); HINGE(tj1, dk3, sD);
            HINGE(tj1, dk4, sA); HINGE(tj1, dk5, sB);
            HINGE(tj1, dk6, sC); HINGE(tj1, dk7, sD);
        }
#undef HINGE
        sum = (sA + sB) + (sC + sD);
        cnt = (float)cw;  // already wave-total; exact (<= 2^17)
    }

    // sum needs lane-reduce; cnt is wave-uniform already
    float wsm = sum;
#pragma unroll
    for (int o = 32; o > 0; o >>= 1) wsm += __shfl_xor(wsm, o, 64);
    if (lane == 0) { sbuf[w] = wsm; cbuf[w] = cnt; }
    __syncthreads();
    if (tid == 0) {
        psum[i] = (sbuf[0] + sbuf[1]) + (sbuf[2] + sbuf[3]);
        pcnt[i] = (cbuf[0] + cbuf[1]) + (cbuf[2] + cbuf[3]);
        __threadfence();  // release partials
        slast = (atomicAdd(done_g, 1u) == (unsigned int)(BS - 1)) ? 1u : 0u;
    }
    __syncthreads();
    if (slast != 0 && tid < 64) {
        __threadfence();  // acquire
        float s = 0.f, c = 0.f;
#pragma unroll
        for (int r = 0; r < 8; ++r) {
            s += psum[r * 64 + tid];
            c += pcnt[r * 64 + tid];
        }
#pragma unroll
        for (int o = 32; o > 0; o >>= 1) {
            s += __shfl_xor(s, o, 64);
            c += __shfl_xor(c, o, 64);
        }
        if (tid == 0) out[0] = s / (c + 1e-7f);
    }
}

extern "C" void kernel_launch(void* const* d_in, const int* in_sizes, int n_in,
                              void* d_out, int out_size, void* d_ws, size_t ws_size,
                              hipStream_t stream) {
    const float* pred = (const float*)d_in[0];
    const int* target = (const int*)d_in[1];
    float* out = (float*)d_out;
    char* base = (char*)d_ws;

    float* dist = (float*)base;                        // 1 MB
    float* psum = (float*)(base + 1048576);            // 2 KB
    float* pcnt = (float*)(base + 1050624);            // 2 KB
    unsigned int* done_g = (unsigned int*)(base + 1052672);

    dim3 gb(16, 16);
    kdistf<<<gb, 64, 0, stream>>>(pred, dist, done_g);
    ktriplet<<<512, 256, 0, stream>>>(dist, target, psum, pcnt, done_g, out);
}

// Round 9
// 38.541 us; speedup vs baseline: 1.0015x; 1.0015x over previous
//
#include <hip/hip_runtime.h>
#include <hip/hip_bf16.h>

#define BS 512
#define MARGIN 0.5f

using short8 = __attribute__((ext_vector_type(8))) short;
using f32x4 = __attribute__((ext_vector_type(4))) float;

__device__ inline short bf16_rne(float x) {
    __hip_bfloat16 h = __float2bfloat16(x);
    return *(short*)&h;
}

// Kernel B (fused normalize+dist): dist[i][j] = sqrt(max(2 - 2*dot_raw*inv_i*inv_j, 0)).
// One wave per 32x32 tile. Raw fp32 rows loaded fragment-shaped, converted to bf16
// in-register, MFMA'd; row norms computed in-wave (shfl chunk-reduce); rescale in epilogue.
__global__ __launch_bounds__(64) void kdistf(const float* __restrict__ pred,
                                             float* __restrict__ dist) {
    const int lane = threadIdx.x;
    const int r0 = blockIdx.y * 32;
    const int c0 = blockIdx.x * 32;
    const int rl = lane & 15;
    const int koff = (lane >> 4) * 8;

    const float* A0 = pred + (r0 + rl) * BS;
    const float* A1 = pred + (r0 + 16 + rl) * BS;
    const float* B0 = pred + (c0 + rl) * BS;
    const float* B1 = pred + (c0 + 16 + rl) * BS;

    f32x4 acc00 = {0.f, 0.f, 0.f, 0.f};
    f32x4 acc01 = {0.f, 0.f, 0.f, 0.f};
    f32x4 acc10 = {0.f, 0.f, 0.f, 0.f};
    f32x4 acc11 = {0.f, 0.f, 0.f, 0.f};
    float na0 = 0.f, na1 = 0.f, nb0 = 0.f, nb1 = 0.f;

#pragma unroll 4
    for (int ks = 0; ks < 16; ++ks) {
        const int k = ks * 32 + koff;
        const f32x4 a0l = *(const f32x4*)(A0 + k);
        const f32x4 a0h = *(const f32x4*)(A0 + k + 4);
        const f32x4 a1l = *(const f32x4*)(A1 + k);
        const f32x4 a1h = *(const f32x4*)(A1 + k + 4);
        const f32x4 b0l = *(const f32x4*)(B0 + k);
        const f32x4 b0h = *(const f32x4*)(B0 + k + 4);
        const f32x4 b1l = *(const f32x4*)(B1 + k);
        const f32x4 b1h = *(const f32x4*)(B1 + k + 4);

        short8 sa0, sa1, sb0, sb1;
#pragma unroll
        for (int j = 0; j < 4; ++j) {
            na0 += a0l[j] * a0l[j] + a0h[j] * a0h[j];
            na1 += a1l[j] * a1l[j] + a1h[j] * a1h[j];
            nb0 += b0l[j] * b0l[j] + b0h[j] * b0h[j];
            nb1 += b1l[j] * b1l[j] + b1h[j] * b1h[j];
            sa0[j] = bf16_rne(a0l[j]); sa0[4 + j] = bf16_rne(a0h[j]);
            sa1[j] = bf16_rne(a1l[j]); sa1[4 + j] = bf16_rne(a1h[j]);
            sb0[j] = bf16_rne(b0l[j]); sb0[4 + j] = bf16_rne(b0h[j]);
            sb1[j] = bf16_rne(b1l[j]); sb1[4 + j] = bf16_rne(b1h[j]);
        }
        acc00 = __builtin_amdgcn_mfma_f32_16x16x32_bf16(sa0, sb0, acc00, 0, 0, 0);
        acc01 = __builtin_amdgcn_mfma_f32_16x16x32_bf16(sa0, sb1, acc01, 0, 0, 0);
        acc10 = __builtin_amdgcn_mfma_f32_16x16x32_bf16(sa1, sb0, acc10, 0, 0, 0);
        acc11 = __builtin_amdgcn_mfma_f32_16x16x32_bf16(sa1, sb1, acc11, 0, 0, 0);
    }

    // chunk-reduce norms: lanes {rl, rl+16, rl+32, rl+48} hold row r0+rl's 4 chunks
    na0 += __shfl_xor(na0, 16, 64); na0 += __shfl_xor(na0, 32, 64);
    na1 += __shfl_xor(na1, 16, 64); na1 += __shfl_xor(na1, 32, 64);
    nb0 += __shfl_xor(nb0, 16, 64); nb0 += __shfl_xor(nb0, 32, 64);
    nb1 += __shfl_xor(nb1, 16, 64); nb1 += __shfl_xor(nb1, 32, 64);
    const float ia0 = 1.0f / fmaxf(sqrtf(na0), 1e-10f);
    const float ia1 = 1.0f / fmaxf(sqrtf(na1), 1e-10f);
    const float ib0 = 1.0f / fmaxf(sqrtf(nb0), 1e-10f);
    const float ib1 = 1.0f / fmaxf(sqrtf(nb1), 1e-10f);

    // C/D layout: col = lane&15, row = (lane>>4)*4 + reg  [m89]
    const int rbase = (lane >> 4) * 4;
#pragma unroll
    for (int fr = 0; fr < 2; ++fr) {
        const float iaSel = (fr == 0) ? ia0 : ia1;
#pragma unroll
        for (int fc = 0; fc < 2; ++fc) {
            f32x4 v = (fr == 0) ? (fc == 0 ? acc00 : acc01) : (fc == 0 ? acc10 : acc11);
            const int col = c0 + fc * 16 + rl;
            const float icol = (fc == 0) ? ib0 : ib1;
#pragma unroll
            for (int r = 0; r < 4; ++r) {
                const float irow = __shfl(iaSel, rbase + r, 64);
                const int row = r0 + fr * 16 + rbase + r;
                float d2 = 2.0f - 2.0f * v[r] * irow * icol;
                d2 = fmaxf(d2, 0.f);
                dist[row * BS + col] = sqrtf(d2);
            }
        }
    }
}

// Kernel C: one block per anchor i. All-scalar registers, readlane broadcast,
// ballot+popcount counting. NO fences, NO atomics — plain per-anchor stores;
// device-wide visibility comes from the kernel boundary.
__global__ __launch_bounds__(256) void ktriplet(const float* __restrict__ dist,
                                                const int* __restrict__ target,
                                                float* __restrict__ psum,
                                                float* __restrict__ pcnt) {
    const int i = blockIdx.x;
    const int tid = threadIdx.x;
    const int lane = tid & 63;
    const int w = tid >> 6;
    __shared__ float sbuf[4];
    __shared__ float cbuf[4];

    float sum = 0.f;
    float cnt = 0.f;

    if (target[i] == 1) {
        const float* drow = dist + i * BS;
        // k-role distances (negatives), named scalars, sentinel +1e30 when masked
        const float d0 = drow[lane];       const float dk0 = (target[lane] == 0)       ? d0 : 1e30f;
        const float d1 = drow[lane + 64];  const float dk1 = (target[lane + 64] == 0)  ? d1 : 1e30f;
        const float d2 = drow[lane + 128]; const float dk2 = (target[lane + 128] == 0) ? d2 : 1e30f;
        const float d3 = drow[lane + 192]; const float dk3 = (target[lane + 192] == 0) ? d3 : 1e30f;
        const float d4 = drow[lane + 256]; const float dk4 = (target[lane + 256] == 0) ? d4 : 1e30f;
        const float d5 = drow[lane + 320]; const float dk5 = (target[lane + 320] == 0) ? d5 : 1e30f;
        const float d6 = drow[lane + 384]; const float dk6 = (target[lane + 384] == 0) ? d6 : 1e30f;
        const float d7 = drow[lane + 448]; const float dk7 = (target[lane + 448] == 0) ? d7 : 1e30f;
        // j-role (positives), this wave's 128 js, margin folded, sentinel -1e9
        const int ja = w * 128 + lane;
        const int jb = ja + 64;
        const float jv0 = (target[ja] == 1 && ja != i) ? drow[ja] + MARGIN : -1e9f;
        const float jv1 = (target[jb] == 1 && jb != i) ? drow[jb] + MARGIN : -1e9f;

        float sA = 0.f, sB = 0.f, sC = 0.f, sD = 0.f;
        unsigned int cw = 0;  // wave-uniform SGPR accumulator (ballot popcounts)

#define HINGE(TJ, DK, SX)                                   \
    do {                                                    \
        const float v_ = (TJ) - (DK);                       \
        SX += fmaxf(v_, 0.f);                               \
        cw += (unsigned int)__popcll(__ballot(v_ > 0.f));   \
    } while (0)

#pragma unroll 4
        for (int jj = 0; jj < 64; ++jj) {
            const float tj0 = __int_as_float(
                __builtin_amdgcn_readlane(__float_as_int(jv0), jj));
            HINGE(tj0, dk0, sA); HINGE(tj0, dk1, sB);
            HINGE(tj0, dk2, sC); HINGE(tj0, dk3, sD);
            HINGE(tj0, dk4, sA); HINGE(tj0, dk5, sB);
            HINGE(tj0, dk6, sC); HINGE(tj0, dk7, sD);
            const float tj1 = __int_as_float(
                __builtin_amdgcn_readlane(__float_as_int(jv1), jj));
            HINGE(tj1, dk0, sA); HINGE(tj1, dk1, sB);
            HINGE(tj1, dk2, sC); HINGE(tj1, dk3, sD);
            HINGE(tj1, dk4, sA); HINGE(tj1, dk5, sB);
            HINGE(tj1, dk6, sC); HINGE(tj1, dk7, sD);
        }
#undef HINGE
        sum = (sA + sB) + (sC + sD);
        cnt = (float)cw;  // already wave-total; exact (<= 2^17)
    }

    // sum needs lane-reduce; cnt is wave-uniform already
    float wsm = sum;
#pragma unroll
    for (int o = 32; o > 0; o >>= 1) wsm += __shfl_xor(wsm, o, 64);
    if (lane == 0) { sbuf[w] = wsm; cbuf[w] = cnt; }
    __syncthreads();
    if (tid == 0) {
        psum[i] = (sbuf[0] + sbuf[1]) + (sbuf[2] + sbuf[3]);
        pcnt[i] = (cbuf[0] + cbuf[1]) + (cbuf[2] + cbuf[3]);
    }
}

// Kernel D: one wave reduces 512 partials + divides. Fixed order, deterministic.
__global__ __launch_bounds__(64) void kfinal(const float* __restrict__ psum,
                                             const float* __restrict__ pcnt,
                                             float* __restrict__ out) {
    const int lane = threadIdx.x;
    float s = 0.f, c = 0.f;
#pragma unroll
    for (int r = 0; r < 8; ++r) {
        s += psum[r * 64 + lane];
        c += pcnt[r * 64 + lane];
    }
#pragma unroll
    for (int o = 32; o > 0; o >>= 1) {
        s += __shfl_xor(s, o, 64);
        c += __shfl_xor(c, o, 64);
    }
    if (lane == 0) out[0] = s / (c + 1e-7f);
}

extern "C" void kernel_launch(void* const* d_in, const int* in_sizes, int n_in,
                              void* d_out, int out_size, void* d_ws, size_t ws_size,
                              hipStream_t stream) {
    const float* pred = (const float*)d_in[0];
    const int* target = (const int*)d_in[1];
    float* out = (float*)d_out;
    char* base = (char*)d_ws;

    float* dist = (float*)base;               // 1 MB
    float* psum = (float*)(base + 1048576);   // 2 KB
    float* pcnt = (float*)(base + 1050624);   // 2 KB

    dim3 gb(16, 16);
    kdistf<<<gb, 64, 0, stream>>>(pred, dist);
    ktriplet<<<512, 256, 0, stream>>>(dist, target, psum, pcnt);
    kfinal<<<1, 64, 0, stream>>>(psum, pcnt, out);
}

// Round 10
// 26.004 us; speedup vs baseline: 1.4843x; 1.4821x over previous
//
#include <hip/hip_runtime.h>
#include <hip/hip_bf16.h>

#define BS 512
#define MARGIN 0.5f

using short8 = __attribute__((ext_vector_type(8))) short;
using f32x4 = __attribute__((ext_vector_type(4))) float;

__device__ inline short bf16_rne(float x) {
    __hip_bfloat16 h = __float2bfloat16(x);
    return *(short*)&h;
}

// Kernel 0: one wave. Stable compaction of positive / negative indices.
__global__ __launch_bounds__(64) void ksetup(const int* __restrict__ target,
                                             int* __restrict__ plist,
                                             int* __restrict__ nlist,
                                             int* __restrict__ counts) {
    const int lane = threadIdx.x;
    int pbase = 0, nbase = 0;
#pragma unroll
    for (int c = 0; c < 8; ++c) {
        const int idx = c * 64 + lane;
        const int t = target[idx];
        const unsigned long long mp = __ballot(t == 1);
        const unsigned long long mn = __ballot(t == 0);
        const unsigned long long below = (1ULL << lane) - 1ULL;
        if (t == 1) plist[pbase + __popcll(mp & below)] = idx;
        else        nlist[nbase + __popcll(mn & below)] = idx;
        pbase += __popcll(mp);
        nbase += __popcll(mn);
    }
    if (lane == 0) { counts[0] = pbase; counts[1] = nbase; }
}

// Kernel 1: dist_c[b][j] for POSITIVE anchors only (rows in pos-space), all cols.
// One wave per 32x32 tile; fused normalize (norms in-wave); bf16 MFMA dots.
__global__ __launch_bounds__(64) void kdistf(const float* __restrict__ pred,
                                             const int* __restrict__ plist,
                                             const int* __restrict__ counts,
                                             float* __restrict__ dist) {
    const int npos = counts[0];
    const int r0 = blockIdx.y * 32;
    if (r0 >= npos) return;
    const int lane = threadIdx.x;
    const int c0 = blockIdx.x * 32;
    const int rl = lane & 15;
    const int koff = (lane >> 4) * 8;

    const int pr0 = min(r0 + rl, npos - 1);
    const int pr1 = min(r0 + 16 + rl, npos - 1);
    const float* A0 = pred + plist[pr0] * BS;
    const float* A1 = pred + plist[pr1] * BS;
    const float* B0 = pred + (c0 + rl) * BS;
    const float* B1 = pred + (c0 + 16 + rl) * BS;

    f32x4 acc00 = {0.f, 0.f, 0.f, 0.f};
    f32x4 acc01 = {0.f, 0.f, 0.f, 0.f};
    f32x4 acc10 = {0.f, 0.f, 0.f, 0.f};
    f32x4 acc11 = {0.f, 0.f, 0.f, 0.f};
    float na0 = 0.f, na1 = 0.f, nb0 = 0.f, nb1 = 0.f;

#pragma unroll 4
    for (int ks = 0; ks < 16; ++ks) {
        const int k = ks * 32 + koff;
        const f32x4 a0l = *(const f32x4*)(A0 + k);
        const f32x4 a0h = *(const f32x4*)(A0 + k + 4);
        const f32x4 a1l = *(const f32x4*)(A1 + k);
        const f32x4 a1h = *(const f32x4*)(A1 + k + 4);
        const f32x4 b0l = *(const f32x4*)(B0 + k);
        const f32x4 b0h = *(const f32x4*)(B0 + k + 4);
        const f32x4 b1l = *(const f32x4*)(B1 + k);
        const f32x4 b1h = *(const f32x4*)(B1 + k + 4);

        short8 sa0, sa1, sb0, sb1;
#pragma unroll
        for (int j = 0; j < 4; ++j) {
            na0 += a0l[j] * a0l[j] + a0h[j] * a0h[j];
            na1 += a1l[j] * a1l[j] + a1h[j] * a1h[j];
            nb0 += b0l[j] * b0l[j] + b0h[j] * b0h[j];
            nb1 += b1l[j] * b1l[j] + b1h[j] * b1h[j];
            sa0[j] = bf16_rne(a0l[j]); sa0[4 + j] = bf16_rne(a0h[j]);
            sa1[j] = bf16_rne(a1l[j]); sa1[4 + j] = bf16_rne(a1h[j]);
            sb0[j] = bf16_rne(b0l[j]); sb0[4 + j] = bf16_rne(b0h[j]);
            sb1[j] = bf16_rne(b1l[j]); sb1[4 + j] = bf16_rne(b1h[j]);
        }
        acc00 = __builtin_amdgcn_mfma_f32_16x16x32_bf16(sa0, sb0, acc00, 0, 0, 0);
        acc01 = __builtin_amdgcn_mfma_f32_16x16x32_bf16(sa0, sb1, acc01, 0, 0, 0);
        acc10 = __builtin_amdgcn_mfma_f32_16x16x32_bf16(sa1, sb0, acc10, 0, 0, 0);
        acc11 = __builtin_amdgcn_mfma_f32_16x16x32_bf16(sa1, sb1, acc11, 0, 0, 0);
    }

    na0 += __shfl_xor(na0, 16, 64); na0 += __shfl_xor(na0, 32, 64);
    na1 += __shfl_xor(na1, 16, 64); na1 += __shfl_xor(na1, 32, 64);
    nb0 += __shfl_xor(nb0, 16, 64); nb0 += __shfl_xor(nb0, 32, 64);
    nb1 += __shfl_xor(nb1, 16, 64); nb1 += __shfl_xor(nb1, 32, 64);
    const float ia0 = 1.0f / fmaxf(sqrtf(na0), 1e-10f);
    const float ia1 = 1.0f / fmaxf(sqrtf(na1), 1e-10f);
    const float ib0 = 1.0f / fmaxf(sqrtf(nb0), 1e-10f);
    const float ib1 = 1.0f / fmaxf(sqrtf(nb1), 1e-10f);

    // C/D layout: col = lane&15, row = (lane>>4)*4 + reg  [m89]
    const int rbase = (lane >> 4) * 4;
#pragma unroll
    for (int fr = 0; fr < 2; ++fr) {
        const float iaSel = (fr == 0) ? ia0 : ia1;
#pragma unroll
        for (int fc = 0; fc < 2; ++fc) {
            f32x4 v = (fr == 0) ? (fc == 0 ? acc00 : acc01) : (fc == 0 ? acc10 : acc11);
            const int col = c0 + fc * 16 + rl;
            const float icol = (fc == 0) ? ib0 : ib1;
#pragma unroll
            for (int r = 0; r < 4; ++r) {
                const float irow = __shfl(iaSel, rbase + r, 64);
                const int rowp = r0 + fr * 16 + rbase + r;  // pos-space row
                float d2 = 2.0f - 2.0f * v[r] * irow * icol;
                d2 = fmaxf(d2, 0.f);
                dist[rowp * BS + col] = sqrtf(d2);
            }
        }
    }
}

// Kernel 2: block b = pos-space anchor. j over compacted positives (readlane
// broadcast from per-wave chunk regs), k = thread's compacted negative(s).
// ~64 hinges/thread typical. No atomics/fences; plain psum/pcnt stores.
__global__ __launch_bounds__(256) void ktriplet(const float* __restrict__ dist,
                                                const int* __restrict__ plist,
                                                const int* __restrict__ nlist,
                                                const int* __restrict__ counts,
                                                float* __restrict__ psum,
                                                float* __restrict__ pcnt) {
    const int b = blockIdx.x;
    const int tid = threadIdx.x;
    const int npos = counts[0];
    if (b >= npos) {
        if (tid == 0) { psum[b] = 0.f; pcnt[b] = 0.f; }
        return;
    }
    const int nneg = counts[1];
    const int lane = tid & 63;
    const int w = tid >> 6;
    __shared__ float sbuf[4];
    __shared__ float cbuf[4];

    const float* drow = dist + b * BS;

    // k-role: this thread's negatives (gathered), sentinel +1e30
    const float bv0 = (tid < nneg) ? drow[nlist[tid]] : 1e30f;
    const float bv1 = (tid + 256 < nneg) ? drow[nlist[tid + 256]] : 1e30f;

    // j-role: wave w owns chunks w and w+4 of compacted positives, margin folded
    const int ja = w * 64 + lane;
    const int jb = (w + 4) * 64 + lane;
    const float av0 = (ja < npos && ja != b) ? drow[plist[ja]] + MARGIN : -1e9f;
    const float av1 = (jb < npos && jb != b) ? drow[plist[jb]] + MARGIN : -1e9f;

    float sum = 0.f;
    unsigned int cw = 0;

#define HINGE(TJ, BK)                                       \
    do {                                                    \
        const float v_ = (TJ) - (BK);                       \
        sum += fmaxf(v_, 0.f);                              \
        cw += (unsigned int)__popcll(__ballot(v_ > 0.f));   \
    } while (0)

    if (nneg > 256) {  // uniform branch (rare path)
        if (w * 64 < npos) {
#pragma unroll 8
            for (int jj = 0; jj < 64; ++jj) {
                const float tj = __int_as_float(
                    __builtin_amdgcn_readlane(__float_as_int(av0), jj));
                HINGE(tj, bv0); HINGE(tj, bv1);
            }
        }
        if ((w + 4) * 64 < npos) {
#pragma unroll 8
            for (int jj = 0; jj < 64; ++jj) {
                const float tj = __int_as_float(
                    __builtin_amdgcn_readlane(__float_as_int(av1), jj));
                HINGE(tj, bv0); HINGE(tj, bv1);
            }
        }
    } else {  // typical: nneg <= 256, one k-slot per thread
        if (w * 64 < npos) {
#pragma unroll 8
            for (int jj = 0; jj < 64; ++jj) {
                const float tj = __int_as_float(
                    __builtin_amdgcn_readlane(__float_as_int(av0), jj));
                HINGE(tj, bv0);
            }
        }
        if ((w + 4) * 64 < npos) {
#pragma unroll 8
            for (int jj = 0; jj < 64; ++jj) {
                const float tj = __int_as_float(
                    __builtin_amdgcn_readlane(__float_as_int(av1), jj));
                HINGE(tj, bv0);
            }
        }
    }
#undef HINGE

    // lane-reduce sum; count already wave-uniform (ballot totals)
    float wsm = sum;
#pragma unroll
    for (int o = 32; o > 0; o >>= 1) wsm += __shfl_xor(wsm, o, 64);
    if (lane == 0) { sbuf[w] = wsm; cbuf[w] = (float)cw; }
    __syncthreads();
    if (tid == 0) {
        psum[b] = (sbuf[0] + sbuf[1]) + (sbuf[2] + sbuf[3]);
        pcnt[b] = (cbuf[0] + cbuf[1]) + (cbuf[2] + cbuf[3]);
    }
}

// Kernel 3: one wave reduces 512 partial slots + divides. Fixed order.
__global__ __launch_bounds__(64) void kfinal(const float* __restrict__ psum,
                                             const float* __restrict__ pcnt,
                                             float* __restrict__ out) {
    const int lane = threadIdx.x;
    float s = 0.f, c = 0.f;
#pragma unroll
    for (int r = 0; r < 8; ++r) {
        s += psum[r * 64 + lane];
        c += pcnt[r * 64 + lane];
    }
#pragma unroll
    for (int o = 32; o > 0; o >>= 1) {
        s += __shfl_xor(s, o, 64);
        c += __shfl_xor(c, o, 64);
    }
    if (lane == 0) out[0] = s / (c + 1e-7f);
}

extern "C" void kernel_launch(void* const* d_in, const int* in_sizes, int n_in,
                              void* d_out, int out_size, void* d_ws, size_t ws_size,
                              hipStream_t stream) {
    const float* pred = (const float*)d_in[0];
    const int* target = (const int*)d_in[1];
    float* out = (float*)d_out;
    char* base = (char*)d_ws;

    float* dist = (float*)base;                     // 512*512*4 = 1 MB (pos-space rows)
    float* psum = (float*)(base + 1048576);         // 2 KB
    float* pcnt = (float*)(base + 1050624);         // 2 KB
    int* plist = (int*)(base + 1052672);            // 2 KB
    int* nlist = (int*)(base + 1054720);            // 2 KB
    int* counts = (int*)(base + 1056768);           // 8 B

    ksetup<<<1, 64, 0, stream>>>(target, plist, nlist, counts);
    dim3 gb(16, 16);
    kdistf<<<gb, 64, 0, stream>>>(pred, plist, counts, dist);
    ktriplet<<<512, 256, 0, stream>>>(dist, plist, nlist, counts, psum, pcnt);
    kfinal<<<1, 64, 0, stream>>>(psum, pcnt, out);
}